// Round 6
// baseline (18076.825 us; speedup 1.0000x reference)
//
#include <hip/hip_runtime.h>
#include <cstdint>
#include <cstddef>

#define NN 128
#define LL 512
#define DD 512
#define HH 1024
#define NJ 4096            // packed gate cols, j = 4*hc + g
#define AK 2048            // A/B row length in bf16 elems (hi | lo planes)
#define NCH 8              // physical K chunks of 128 (per plane)

// LDS plane offsets (shorts) within one 48KB buffer
#define AHI 0
#define ALO 4096
#define BHI 8192
#define BLO 16384

typedef __attribute__((ext_vector_type(8))) short short8;
typedef __attribute__((ext_vector_type(4))) float f32x4;

__device__ __forceinline__ unsigned short f2bf(float x) {
  union { float f; unsigned u; } v; v.f = x;
  unsigned r = v.u + 0x7FFFu + ((v.u >> 16) & 1u);
  return (unsigned short)(r >> 16);
}
__device__ __forceinline__ float bf2f(unsigned short b) {
  union { unsigned u; float f; } v; v.u = ((unsigned)b) << 16;
  return v.f;
}
__device__ __forceinline__ float sigf(float x) { return 1.0f / (1.0f + __expf(-x)); }

__device__ __forceinline__ void glds16(const void* g, const void* l) {
  __builtin_amdgcn_global_load_lds(
      (const __attribute__((address_space(1))) unsigned int*)g,
      (__attribute__((address_space(3))) unsigned int*)l, 16, 0, 0);
}

// ---------------- sT[l*NN + n] = sum_d X[n,l,d] ----------------
__global__ __launch_bounds__(256)
void sum_rows_kernel(const float* __restrict__ X, float* __restrict__ sT) {
  int row  = blockIdx.x * 4 + (threadIdx.x >> 6);
  int lane = threadIdx.x & 63;
  const float* x = X + (size_t)row * DD + lane * 8;
  float4 a = *(const float4*)x;
  float4 b = *(const float4*)(x + 4);
  float v = (a.x + a.y) + (a.z + a.w) + (b.x + b.y) + (b.z + b.w);
#pragma unroll
  for (int off = 32; off > 0; off >>= 1) v += __shfl_down(v, off, 64);
  if (lane == 0) {
    int n = row >> 9, l = row & 511;
    sT[l * NN + n] = v;
  }
}

// ---------------- split W into bf16 hi|lo, gate-interleaved rows ----------------
__global__ __launch_bounds__(256)
void wsplit_kernel(const float* __restrict__ Wi, const float* __restrict__ Wf,
                   const float* __restrict__ Wg, const float* __restrict__ Wo,
                   unsigned short* __restrict__ B) {
  int idx = blockIdx.x * 256 + threadIdx.x;    // NJ*128 threads
  int j = idx >> 7;
  int k = (idx & 127) << 3;
  int hc = j >> 2, g = j & 3;
  const float* W = (g == 0) ? Wi : (g == 1) ? Wf : (g == 2) ? Wg : Wo;
  const float4 x0 = *(const float4*)(W + (size_t)hc * HH + k);
  const float4 x1 = *(const float4*)(W + (size_t)hc * HH + k + 4);
  float xv[8] = {x0.x, x0.y, x0.z, x0.w, x1.x, x1.y, x1.z, x1.w};
  unsigned short* dhi = B + (size_t)j * AK + k;
  unsigned short* dlo = dhi + 1024;
#pragma unroll
  for (int e = 0; e < 8; ++e) {
    unsigned short hi = f2bf(xv[e]);
    dhi[e] = hi;
    dlo[e] = f2bf(xv[e] - bf2f(hi));
  }
}

// ---------------- pack lambda / (binv+b) gate-interleaved ----------------
__global__ __launch_bounds__(256)
void pack_kernel(const float* li, const float* lf, const float* lg, const float* lo_,
                 const float* bvi, const float* bvf, const float* bvg, const float* bvo,
                 const float* bi, const float* bf_, const float* bg, const float* bo,
                 float* __restrict__ lamP, float* __restrict__ biasP) {
  int j = blockIdx.x * 256 + threadIdx.x;
  int hc = j >> 2, g = j & 3;
  const float* lam = (g == 0) ? li : (g == 1) ? lf : (g == 2) ? lg : lo_;
  const float* bv  = (g == 0) ? bvi : (g == 1) ? bvf : (g == 2) ? bvg : bvo;
  const float* bb  = (g == 0) ? bi : (g == 1) ? bf_ : (g == 2) ? bg : bo;
  lamP[j] = lam[hc];
  biasP[j] = bv[hc] + bb[hc];
}

// ---------------- persistent LSTM: all 512 steps in one kernel ----------------
// PLAIN launch: 256 blocks x 256 thr, 96 KB LDS -> exactly 1 block/CU,
// grid == CU count (guide-sanctioned manual residency, __launch_bounds__(256,1)).
// 4 independent Mt groups of 64 blocks, each synced by a monotonic counter:
// producer: stores -> __syncthreads (drains vmcnt; L1 write-through -> L2)
//           -> lane0 atomicAdd RELEASE/agent (L2 writeback to coherence point)
// consumer: per-WAVE lane-0 RELAXED spin + ACQUIRE/agent fence -> s_barrier.
__global__ __launch_bounds__(256, 1)
void persist_kernel(const unsigned short* __restrict__ Bbuf,
                    const float* __restrict__ sT,
                    const float* __restrict__ lamP,
                    const float* __restrict__ biasP,
                    float* __restrict__ out,
                    unsigned short* __restrict__ A0g,
                    unsigned short* __restrict__ A1g,
                    unsigned* __restrict__ cnt)
{
  __shared__ alignas(16) short lds[2][24576];   // 48 KB x 2

  const int tid = threadIdx.x;
  const int ln  = tid & 63;
  const int w   = tid >> 6;          // wave 0..3

  const int bid = blockIdx.x;
  const int wl  = (bid & 7) * 32 + (bid >> 3);   // XCD-contiguous Nt
  const int Nt  = wl >> 2;           // 0..63
  const int Mt  = wl & 3;            // 0..3
  const int n0  = Mt * 32;
  const int j0  = Nt * 64;
  unsigned* mycnt = cnt + Mt;

  const int ps = ln & 15;
  const int rr = ln >> 4;

  // --- staging tables: A 16 pieces (4/wave), B 32 pieces (8/wave), 1KB each ---
  int aoffsrc[4]; int ldsA[4];
#pragma unroll
  for (int i = 0; i < 4; ++i) {
    int pa = w * 4 + i;              // 0..15
    int plane = (pa >= 8) ? 1 : 0;
    int pr = pa - plane * 8;         // 0..7
    int r  = pr * 4 + rr;            // 0..31
    int sp = (ps & 8) | ((ps ^ r) & 7);
    aoffsrc[i] = ((n0 + r) * AK + plane * 1024 + sp * 8) * 2;   // byte offset
    ldsA[i] = (plane ? ALO : AHI) + pr * 512;
  }
  const char* srcB[8]; int ldsB[8];
#pragma unroll
  for (int i = 0; i < 8; ++i) {
    int pb = w * 8 + i;              // 0..31
    int plane = (pb >= 16) ? 1 : 0;
    int pr = pb - plane * 16;        // 0..15
    int r  = pr * 4 + rr;            // 0..63
    int sp = (ps & 8) | ((ps ^ r) & 7);
    srcB[i] = (const char*)(Bbuf + (size_t)(j0 + r) * AK + plane * 1024 + sp * 8);
    ldsB[i] = (plane ? BLO : BHI) + pr * 512;
  }

  // --- fragment read offsets (shorts, within a plane) ---
  int aoff[2][4], boff[4];
#pragma unroll
  for (int mf = 0; mf < 2; ++mf)
#pragma unroll
    for (int sl = 0; sl < 4; ++sl) {
      int rA = mf * 16 + (ln & 15);
      int s  = sl * 4 + (ln >> 4);
      aoff[mf][sl] = rA * 128 + (((s & 8) | ((s ^ rA) & 7)) << 3);
    }
  {
    int rB = w * 16 + (ln & 15);
#pragma unroll
    for (int sl = 0; sl < 4; ++sl) {
      int s = sl * 4 + (ln >> 4);
      boff[sl] = rB * 128 + (((s & 8) | ((s ^ rB) & 7)) << 3);
    }
  }

  // epilogue constants
  const int jj = j0 + w * 16 + (ln & 15);
  const float lamv = lamP[jj];
  const float biav = biasP[jj];
  const int rbase = rr * 4;
  float creg[2][4] = {{0.f,0.f,0.f,0.f},{0.f,0.f,0.f,0.f}};

  for (int t = 0; t < LL; ++t) {
    unsigned short* Acur = (t & 1) ? A1g : A0g;
    f32x4 acc0 = {0.f,0.f,0.f,0.f};
    f32x4 acc1 = {0.f,0.f,0.f,0.f};

    if (t > 0) {
      const char* Ab = (const char*)((t & 1) ? A0g : A1g);   // A written at t-1
      // B chunks 0,1: issue BEFORE the spin (step-invariant data)
#pragma unroll
      for (int i = 0; i < 8; ++i) glds16(srcB[i], &lds[0][ldsB[i]]);
#pragma unroll
      for (int i = 0; i < 8; ++i) glds16(srcB[i] + 256, &lds[1][ldsB[i]]);

      // per-wave spin: each wave's lane 0 waits + does its own acquire
      if (ln == 0) {
        unsigned tgt = 64u * (unsigned)t;
        while (__hip_atomic_load(mycnt, __ATOMIC_RELAXED, __HIP_MEMORY_SCOPE_AGENT) < tgt)
          __builtin_amdgcn_s_sleep(4);
        __builtin_amdgcn_fence(__ATOMIC_ACQUIRE, "agent");
      }
      __builtin_amdgcn_s_barrier();
      __builtin_amdgcn_sched_barrier(0);

      // A chunks 0,1
#pragma unroll
      for (int i = 0; i < 4; ++i) glds16(Ab + aoffsrc[i], &lds[0][ldsA[i]]);
#pragma unroll
      for (int i = 0; i < 4; ++i) glds16(Ab + aoffsrc[i] + 256, &lds[1][ldsA[i]]);

#pragma unroll
      for (int c = 0; c < NCH; ++c) {
        __builtin_amdgcn_s_barrier();            // compute(c-1) done: buf free
        if (c >= 1 && c < 7) {
          const int co = (c + 1) * 256;
          const int b2 = (c + 1) & 1;
#pragma unroll
          for (int i = 0; i < 8; ++i) glds16(srcB[i] + co, &lds[b2][ldsB[i]]);
#pragma unroll
          for (int i = 0; i < 4; ++i) glds16(Ab + aoffsrc[i] + co, &lds[b2][ldsA[i]]);
        }
        if (c == 0)      asm volatile("s_waitcnt vmcnt(4)" ::: "memory");
        else if (c < 7)  asm volatile("s_waitcnt vmcnt(12)" ::: "memory");
        else             asm volatile("s_waitcnt vmcnt(0)" ::: "memory");
        __builtin_amdgcn_s_barrier();            // chunk c visible to all waves
        const int b = c & 1;
#pragma unroll
        for (int sl = 0; sl < 4; ++sl) {
          short8 ahi0 = *(const short8*)&lds[b][AHI + aoff[0][sl]];
          short8 ahi1 = *(const short8*)&lds[b][AHI + aoff[1][sl]];
          short8 alo0 = *(const short8*)&lds[b][ALO + aoff[0][sl]];
          short8 alo1 = *(const short8*)&lds[b][ALO + aoff[1][sl]];
          short8 bhi  = *(const short8*)&lds[b][BHI + boff[sl]];
          short8 blo  = *(const short8*)&lds[b][BLO + boff[sl]];
          acc0 = __builtin_amdgcn_mfma_f32_16x16x32_bf16(ahi0, bhi, acc0, 0, 0, 0);
          acc0 = __builtin_amdgcn_mfma_f32_16x16x32_bf16(ahi0, blo, acc0, 0, 0, 0);
          acc0 = __builtin_amdgcn_mfma_f32_16x16x32_bf16(alo0, bhi, acc0, 0, 0, 0);
          acc1 = __builtin_amdgcn_mfma_f32_16x16x32_bf16(ahi1, bhi, acc1, 0, 0, 0);
          acc1 = __builtin_amdgcn_mfma_f32_16x16x32_bf16(ahi1, blo, acc1, 0, 0, 0);
          acc1 = __builtin_amdgcn_mfma_f32_16x16x32_bf16(alo1, bhi, acc1, 0, 0, 0);
        }
      }
    }

    // ---- epilogue: fuse 4 gates (adjacent lanes) -> c,h ; emit h + h_hi/h_lo ----
#pragma unroll
    for (int mf = 0; mf < 2; ++mf) {
      const int m0 = n0 + mf * 16 + rbase;
#pragma unroll
      for (int r = 0; r < 4; ++r) {
        const int m = m0 + r;
        float a = (mf == 0) ? acc0[r] : acc1[r];
        float v = sigf(a + sT[t * NN + m] * lamv + biav);
        const int base = ln & ~3;
        float vi = __shfl(v, base + 0, 64);
        float vf = __shfl(v, base + 1, 64);
        float vg = __shfl(v, base + 2, 64);
        float vo = __shfl(v, base + 3, 64);
        if ((ln & 3) == 0) {
          const int hc = jj >> 2;
          float cn = vf * creg[mf][r] + vi * vg;
          creg[mf][r] = cn;
          float hn = vo * sigf(cn);
          out[(size_t)m * (LL * HH) + (size_t)t * HH + hc] = hn;
          unsigned short h2 = f2bf(hn);
          Acur[(size_t)m * AK + hc] = h2;
          Acur[(size_t)m * AK + 1024 + hc] = f2bf(hn - bf2f(h2));
        }
      }
    }

    __syncthreads();                              // drain stores of all waves
    if (tid == 0)
      __hip_atomic_fetch_add(mycnt, 1u, __ATOMIC_RELEASE, __HIP_MEMORY_SCOPE_AGENT);
  }
}

extern "C" void kernel_launch(void* const* d_in, const int* in_sizes, int n_in,
                              void* d_out, int out_size, void* d_ws, size_t ws_size,
                              hipStream_t stream) {
  const float* X    = (const float*)d_in[0];
  const float* lami = (const float*)d_in[1];
  const float* bvi  = (const float*)d_in[2];
  const float* Wi   = (const float*)d_in[3];
  const float* bi   = (const float*)d_in[4];
  const float* lamf = (const float*)d_in[5];
  const float* bvf  = (const float*)d_in[6];
  const float* Wf   = (const float*)d_in[7];
  const float* bf_  = (const float*)d_in[8];
  const float* lamg = (const float*)d_in[9];
  const float* bvg  = (const float*)d_in[10];
  const float* Wg   = (const float*)d_in[11];
  const float* bg   = (const float*)d_in[12];
  const float* lamo = (const float*)d_in[13];
  const float* bvo  = (const float*)d_in[14];
  const float* Wo   = (const float*)d_in[15];
  const float* bo   = (const float*)d_in[16];

  float* out  = (float*)d_out;

  // workspace layout (~17.3 MB)
  float* sT    = (float*)d_ws;                         // 512*128  f32
  float* lamP  = sT + (size_t)NN * LL;                 // 4096 f32
  float* biasP = lamP + NJ;                            // 4096 f32
  unsigned short* A0 = (unsigned short*)(biasP + NJ);  // 128*2048 bf16
  unsigned short* A1 = A0 + (size_t)NN * AK;           // 128*2048 bf16
  unsigned short* Bb = A1 + (size_t)NN * AK;           // 4096*2048 bf16 (16 MB)
  unsigned* cntp = (unsigned*)(Bb + (size_t)NJ * AK);  // 4 counters

  hipMemsetAsync(cntp, 0, 4 * sizeof(unsigned), stream);
  sum_rows_kernel<<<(NN * LL) / 4, 256, 0, stream>>>(X, sT);
  wsplit_kernel<<<(NJ * 128) / 256, 256, 0, stream>>>(Wi, Wf, Wg, Wo, Bb);
  pack_kernel<<<NJ / 256, 256, 0, stream>>>(lami, lamf, lamg, lamo,
                                            bvi, bvf, bvg, bvo,
                                            bi, bf_, bg, bo, lamP, biasP);

  persist_kernel<<<dim3(256), dim3(256), 0, stream>>>(Bb, sT, lamP, biasP,
                                                      out, A0, A1, cntp);
}

// Round 8
// 12529.875 us; speedup vs baseline: 1.4427x; 1.4427x over previous
//
#include <hip/hip_runtime.h>
#include <cstdint>
#include <cstddef>

#define NN 128
#define LL 512
#define DD 512
#define HH 1024
#define NJ 4096            // packed gate cols, j = 4*hc + g
#define BKR 2048           // Bbuf row length (bf16): hi[1024] | lo[1024]
#define AROW 1024          // Ag row length (u32): hi-pairs[0..511] | lo-pairs[512..1023]
#define NCH 8              // K chunks of 128

// LDS plane offsets (shorts) within one 48KB buffer
#define AHI 0
#define ALO 4096
#define BHI 8192
#define BLO 16384

typedef __attribute__((ext_vector_type(8))) short short8;
typedef __attribute__((ext_vector_type(4))) float f32x4;
typedef __attribute__((ext_vector_type(4))) unsigned u32x4;

__device__ __forceinline__ unsigned short f2bf(float x) {
  union { float f; unsigned u; } v; v.f = x;
  unsigned r = v.u + 0x7FFFu + ((v.u >> 16) & 1u);
  return (unsigned short)(r >> 16);
}
__device__ __forceinline__ float bf2f(unsigned short b) {
  union { unsigned u; float f; } v; v.u = ((unsigned)b) << 16;
  return v.f;
}
__device__ __forceinline__ float sigf(float x) { return 1.0f / (1.0f + __expf(-x)); }

__device__ __forceinline__ void glds16(const void* g, const void* l) {
  __builtin_amdgcn_global_load_lds(
      (const __attribute__((address_space(1))) unsigned int*)g,
      (__attribute__((address_space(3))) unsigned int*)l, 16, 0, 0);
}

// ---------------- sT[l*NN + n] = sum_d X[n,l,d] ----------------
__global__ __launch_bounds__(256)
void sum_rows_kernel(const float* __restrict__ X, float* __restrict__ sT) {
  int row  = blockIdx.x * 4 + (threadIdx.x >> 6);
  int lane = threadIdx.x & 63;
  const float* x = X + (size_t)row * DD + lane * 8;
  float4 a = *(const float4*)x;
  float4 b = *(const float4*)(x + 4);
  float v = (a.x + a.y) + (a.z + a.w) + (b.x + b.y) + (b.z + b.w);
#pragma unroll
  for (int off = 32; off > 0; off >>= 1) v += __shfl_down(v, off, 64);
  if (lane == 0) {
    int n = row >> 9, l = row & 511;
    sT[l * NN + n] = v;
  }
}

// ---------------- split W into bf16 hi|lo, gate-interleaved rows ----------------
__global__ __launch_bounds__(256)
void wsplit_kernel(const float* __restrict__ Wi, const float* __restrict__ Wf,
                   const float* __restrict__ Wg, const float* __restrict__ Wo,
                   unsigned short* __restrict__ B) {
  int idx = blockIdx.x * 256 + threadIdx.x;    // NJ*128 threads
  int j = idx >> 7;
  int k = (idx & 127) << 3;
  int hc = j >> 2, g = j & 3;
  const float* W = (g == 0) ? Wi : (g == 1) ? Wf : (g == 2) ? Wg : Wo;
  const float4 x0 = *(const float4*)(W + (size_t)hc * HH + k);
  const float4 x1 = *(const float4*)(W + (size_t)hc * HH + k + 4);
  float xv[8] = {x0.x, x0.y, x0.z, x0.w, x1.x, x1.y, x1.z, x1.w};
  unsigned short* dhi = B + (size_t)j * BKR + k;
  unsigned short* dlo = dhi + 1024;
#pragma unroll
  for (int e = 0; e < 8; ++e) {
    unsigned short hi = f2bf(xv[e]);
    dhi[e] = hi;
    dlo[e] = f2bf(xv[e] - bf2f(hi));
  }
}

// ---------------- pack lambda / (binv+b) gate-interleaved ----------------
__global__ __launch_bounds__(256)
void pack_kernel(const float* li, const float* lf, const float* lg, const float* lo_,
                 const float* bvi, const float* bvf, const float* bvg, const float* bvo,
                 const float* bi, const float* bf_, const float* bg, const float* bo,
                 float* __restrict__ lamP, float* __restrict__ biasP) {
  int j = blockIdx.x * 256 + threadIdx.x;
  int hc = j >> 2, g = j & 3;
  const float* lam = (g == 0) ? li : (g == 1) ? lf : (g == 2) ? lg : lo_;
  const float* bv  = (g == 0) ? bvi : (g == 1) ? bvf : (g == 2) ? bvg : bvo;
  const float* bb  = (g == 0) ? bi : (g == 1) ? bf_ : (g == 2) ? bg : bo;
  lamP[j] = lam[hc];
  biasP[j] = bv[hc] + bb[hc];
}

// ---------------- persistent LSTM: fence-free MALL handshake ----------------
// 256 blocks x 256 thr, 96 KB LDS -> 1 block/CU, all co-resident.
// A (h hi/lo) exchanged as u32 bf16-pairs through the coherence point:
//   producer: __hip_atomic_store RELAXED/AGENT (write-through), __syncthreads
//             (per-wave vmcnt drain => at MALL), then per-block flag store.
//   consumer: wave0 polls 64 per-block flags with ONE coalesced wave load +
//             __all (no shared-address contention), then agent atomic loads
//             of A -> registers -> swizzled ds_write_b128.
// B: plain global_load_lds, L2-resident forever (no invalidates anywhere).
__global__ __launch_bounds__(256, 1)
void persist_kernel(const unsigned short* __restrict__ Bbuf,
                    const float* __restrict__ sT,
                    const float* __restrict__ lamP,
                    const float* __restrict__ biasP,
                    float* __restrict__ out,
                    unsigned* __restrict__ Ag0,
                    unsigned* __restrict__ Ag1,
                    unsigned* __restrict__ flags)
{
  __shared__ alignas(16) short lds[2][24576];   // 48 KB x 2

  const int tid = threadIdx.x;
  const int ln  = tid & 63;
  const int w   = tid >> 6;

  const int bid = blockIdx.x;
  const int wl  = (bid & 7) * 32 + (bid >> 3);   // XCD-contiguous
  const int Nt  = wl >> 2;           // 0..63
  const int Mt  = wl & 3;            // 0..3
  const int n0  = Mt * 32;
  const int j0  = Nt * 64;
  unsigned* gf = flags + Mt * 64;

  const int ps = ln & 15;
  const int rr = ln >> 4;

  // --- B staging pieces: 32 x 1KB per chunk, 8 per wave (R6-proven) ---
  const char* srcB[8]; int ldsB[8];
#pragma unroll
  for (int i = 0; i < 8; ++i) {
    int pb = w * 8 + i;
    int plane = (pb >= 16) ? 1 : 0;
    int pr = pb - plane * 16;
    int r  = pr * 4 + rr;
    int sp = (ps & 8) | ((ps ^ r) & 7);
    srcB[i] = (const char*)(Bbuf + (size_t)(j0 + r) * BKR + plane * 1024 + sp * 8);
    ldsB[i] = (plane ? BLO : BHI) + pr * 512;
  }

  // --- A consumer mapping: thread -> row ar, slots ssb/ssb+1, both planes ---
  const int ar  = tid >> 3;          // 0..31
  const int ssb = (tid & 7) * 2;     // 16B-slot base within 128k chunk
  const size_t abase = (size_t)(n0 + ar) * AROW;
  int wrA[2][2];
#pragma unroll
  for (int p = 0; p < 2; ++p)
#pragma unroll
    for (int q = 0; q < 2; ++q) {
      int ss = ssb + q;
      int sp = (ss & 8) | ((ss ^ ar) & 7);
      wrA[p][q] = (p ? ALO : AHI) + ar * 128 + sp * 8;
    }

  // --- fragment read offsets (R6-verified) ---
  int aoff[2][4], boff[4];
#pragma unroll
  for (int mf = 0; mf < 2; ++mf)
#pragma unroll
    for (int sl = 0; sl < 4; ++sl) {
      int rA = mf * 16 + (ln & 15);
      int s  = sl * 4 + (ln >> 4);
      aoff[mf][sl] = rA * 128 + (((s & 8) | ((s ^ rA) & 7)) << 3);
    }
  {
    int rB = w * 16 + (ln & 15);
#pragma unroll
    for (int sl = 0; sl < 4; ++sl) {
      int s = sl * 4 + (ln >> 4);
      boff[sl] = rB * 128 + (((s & 8) | ((s ^ rB) & 7)) << 3);
    }
  }

  // epilogue constants
  const int jj = j0 + w * 16 + (ln & 15);
  const float lamv = lamP[jj];
  const float biav = biasP[jj];
  const int rbase = rr * 4;
  const int hcst = jj >> 2;
  float creg[2][4] = {{0.f,0.f,0.f,0.f},{0.f,0.f,0.f,0.f}};

  unsigned av0[2][2][4], av1[2][2][4];

  auto issueA = [&](unsigned (&av)[2][2][4], const unsigned* base, int c) {
#pragma unroll
    for (int p = 0; p < 2; ++p)
#pragma unroll
      for (int q = 0; q < 2; ++q)
#pragma unroll
        for (int j = 0; j < 4; ++j)
          av[p][q][j] = __hip_atomic_load(
              (unsigned*)base + abase + p * 512 + 64 * c + 4 * (ssb + q) + j,
              __ATOMIC_RELAXED, __HIP_MEMORY_SCOPE_AGENT);
  };

  for (int t = 0; t < LL; ++t) {
    unsigned* Acur = (t & 1) ? Ag1 : Ag0;
    const unsigned* Aprv = (t & 1) ? Ag0 : Ag1;
    f32x4 acc0 = {0.f,0.f,0.f,0.f};
    f32x4 acc1 = {0.f,0.f,0.f,0.f};

    if (t > 0) {
      // B chunk 0 prefetch BEFORE the wait (step-invariant data)
#pragma unroll
      for (int i = 0; i < 8; ++i) glds16(srcB[i], &lds[0][ldsB[i]]);

      // zero-contention flag poll: wave0, one coalesced load of 64 flags
      if (w == 0) {
        for (;;) {
          unsigned v = __hip_atomic_load(&gf[ln], __ATOMIC_RELAXED,
                                         __HIP_MEMORY_SCOPE_AGENT);
          if (__all((int)v >= t)) break;
          __builtin_amdgcn_s_sleep(8);
        }
      }
      __builtin_amdgcn_s_barrier();
      __builtin_amdgcn_sched_barrier(0);

      issueA(av0, Aprv, 0);
      __builtin_amdgcn_sched_barrier(0);
      issueA(av1, Aprv, 1);
      __builtin_amdgcn_sched_barrier(0);

#pragma unroll
      for (int c = 0; c < NCH; ++c) {
        const int b = c & 1;
        __builtin_amdgcn_s_barrier();            // compute(c-1) done: buffers free
        __builtin_amdgcn_sched_barrier(0);
        if (c < 7) asm volatile("s_waitcnt vmcnt(16)" ::: "memory");  // A(c)+B(c) landed
        else       asm volatile("s_waitcnt vmcnt(0)"  ::: "memory");
        __builtin_amdgcn_sched_barrier(0);
        // A(c): regs -> swizzled LDS
        {
          unsigned (&av)[2][2][4] = b ? av1 : av0;
#pragma unroll
          for (int p = 0; p < 2; ++p)
#pragma unroll
            for (int q = 0; q < 2; ++q) {
              u32x4 vv = { av[p][q][0], av[p][q][1], av[p][q][2], av[p][q][3] };
              *(u32x4*)&lds[b][wrA[p][q]] = vv;
            }
        }
        __builtin_amdgcn_sched_barrier(0);
        if (c < 7) {
#pragma unroll
          for (int i = 0; i < 8; ++i)
            glds16(srcB[i] + (c + 1) * 256, &lds[b ^ 1][ldsB[i]]);
        }
        __builtin_amdgcn_sched_barrier(0);
        if (c < 6) {
          unsigned (&av)[2][2][4] = b ? av1 : av0;
          issueA(av, Aprv, c + 2);
        }
        __builtin_amdgcn_sched_barrier(0);
        asm volatile("s_waitcnt lgkmcnt(0)" ::: "memory");
        __builtin_amdgcn_sched_barrier(0);
        __builtin_amdgcn_s_barrier();            // chunk c visible block-wide
        __builtin_amdgcn_sched_barrier(0);
#pragma unroll
        for (int sl = 0; sl < 4; ++sl) {
          short8 ahi0 = *(const short8*)&lds[b][AHI + aoff[0][sl]];
          short8 ahi1 = *(const short8*)&lds[b][AHI + aoff[1][sl]];
          short8 alo0 = *(const short8*)&lds[b][ALO + aoff[0][sl]];
          short8 alo1 = *(const short8*)&lds[b][ALO + aoff[1][sl]];
          short8 bhi  = *(const short8*)&lds[b][BHI + boff[sl]];
          short8 blo  = *(const short8*)&lds[b][BLO + boff[sl]];
          acc0 = __builtin_amdgcn_mfma_f32_16x16x32_bf16(ahi0, bhi, acc0, 0, 0, 0);
          acc0 = __builtin_amdgcn_mfma_f32_16x16x32_bf16(ahi0, blo, acc0, 0, 0, 0);
          acc0 = __builtin_amdgcn_mfma_f32_16x16x32_bf16(alo0, bhi, acc0, 0, 0, 0);
          acc1 = __builtin_amdgcn_mfma_f32_16x16x32_bf16(ahi1, bhi, acc1, 0, 0, 0);
          acc1 = __builtin_amdgcn_mfma_f32_16x16x32_bf16(ahi1, blo, acc1, 0, 0, 0);
          acc1 = __builtin_amdgcn_mfma_f32_16x16x32_bf16(alo1, bhi, acc1, 0, 0, 0);
        }
      }
    }

    // ---- epilogue: gates -> c,h ; h to out; h hi/lo u32-pairs to MALL ----
#pragma unroll
    for (int mf = 0; mf < 2; ++mf) {
      const int m0 = n0 + mf * 16 + rbase;
#pragma unroll
      for (int r = 0; r < 4; ++r) {
        const int m = m0 + r;
        float a = (mf == 0) ? acc0[r] : acc1[r];
        float v = sigf(a + sT[t * NN + m] * lamv + biav);
        const int qb = ln & ~3;
        float vi = __shfl(v, qb + 0, 64);
        float vf = __shfl(v, qb + 1, 64);
        float vg = __shfl(v, qb + 2, 64);
        float vo = __shfl(v, qb + 3, 64);
        float cn = vf * creg[mf][r] + vi * vg;   // garbage on non-leader lanes, unused
        creg[mf][r] = cn;
        float hn = vo * sigf(cn);
        unsigned uhi = f2bf(hn);
        unsigned ulo = f2bf(hn - bf2f((unsigned short)uhi));
        int phi = __shfl((int)uhi, (ln + 4) & 63, 64);
        int plo = __shfl((int)ulo, (ln + 4) & 63, 64);
        if ((ln & 3) == 0)
          out[(size_t)m * (LL * HH) + (size_t)t * HH + hcst] = hn;
        if ((ln & 7) == 0) {           // hcst even here; pair (hc, hc+1)
          size_t ai = (size_t)m * AROW + (hcst >> 1);
          __hip_atomic_store(Acur + ai, uhi | ((unsigned)phi << 16),
                             __ATOMIC_RELAXED, __HIP_MEMORY_SCOPE_AGENT);
          __hip_atomic_store(Acur + ai + 512, ulo | ((unsigned)plo << 16),
                             __ATOMIC_RELAXED, __HIP_MEMORY_SCOPE_AGENT);
        }
      }
    }

    __syncthreads();   // every wave's stores vmcnt-retired => at coherence point
    if (tid == 0)
      __hip_atomic_store(&flags[Mt * 64 + Nt], (unsigned)(t + 1),
                         __ATOMIC_RELAXED, __HIP_MEMORY_SCOPE_AGENT);
  }
}

extern "C" void kernel_launch(void* const* d_in, const int* in_sizes, int n_in,
                              void* d_out, int out_size, void* d_ws, size_t ws_size,
                              hipStream_t stream) {
  const float* X    = (const float*)d_in[0];
  const float* lami = (const float*)d_in[1];
  const float* bvi  = (const float*)d_in[2];
  const float* Wi   = (const float*)d_in[3];
  const float* bi   = (const float*)d_in[4];
  const float* lamf = (const float*)d_in[5];
  const float* bvf  = (const float*)d_in[6];
  const float* Wf   = (const float*)d_in[7];
  const float* bf_  = (const float*)d_in[8];
  const float* lamg = (const float*)d_in[9];
  const float* bvg  = (const float*)d_in[10];
  const float* Wg   = (const float*)d_in[11];
  const float* bg   = (const float*)d_in[12];
  const float* lamo = (const float*)d_in[13];
  const float* bvo  = (const float*)d_in[14];
  const float* Wo   = (const float*)d_in[15];
  const float* bo   = (const float*)d_in[16];

  float* out = (float*)d_out;

  // workspace layout (~17.5 MB)
  float* sT    = (float*)d_ws;                          // 512*128 f32 (256 KB)
  float* lamP  = sT + (size_t)NN * LL;                  // 4096 f32
  float* biasP = lamP + NJ;                             // 4096 f32
  unsigned* Ag0 = (unsigned*)(biasP + NJ);              // 128*1024 u32 (512 KB)
  unsigned* Ag1 = Ag0 + (size_t)NN * AROW;              // 128*1024 u32
  unsigned short* Bb = (unsigned short*)(Ag1 + (size_t)NN * AROW);  // 4096*2048 bf16 (16 MB)
  unsigned* flags = (unsigned*)(Bb + (size_t)NJ * BKR); // 256 u32

  hipMemsetAsync(flags, 0, 256 * sizeof(unsigned), stream);
  sum_rows_kernel<<<(NN * LL) / 4, 256, 0, stream>>>(X, sT);
  wsplit_kernel<<<(NJ * 128) / 256, 256, 0, stream>>>(Wi, Wf, Wg, Wo, Bb);
  pack_kernel<<<NJ / 256, 256, 0, stream>>>(lami, lamf, lamg, lamo,
                                            bvi, bvf, bvg, bvo,
                                            bi, bf_, bg, bo, lamP, biasP);

  persist_kernel<<<dim3(256), dim3(256), 0, stream>>>(Bb, sT, lamP, biasP,
                                                      out, Ag0, Ag1, flags);
}

// Round 9
// 8314.275 us; speedup vs baseline: 2.1742x; 1.5070x over previous
//
#include <hip/hip_runtime.h>
#include <cstdint>
#include <cstddef>

#define NN 128
#define LL 512
#define DD 512
#define HH 1024
#define NJ 4096            // packed gate cols, j = 4*hc + g
#define AK 2048            // A/B row length in bf16 elems (hi | lo planes)
#define NCH 8              // physical K chunks of 128 (per plane)

// LDS plane offsets (shorts) within one 48KB buffer
#define AHI 0
#define ALO 4096
#define BHI 8192
#define BLO 16384

typedef __attribute__((ext_vector_type(8))) short short8;
typedef __attribute__((ext_vector_type(4))) float f32x4;

__device__ __forceinline__ unsigned short f2bf(float x) {
  union { float f; unsigned u; } v; v.f = x;
  unsigned r = v.u + 0x7FFFu + ((v.u >> 16) & 1u);
  return (unsigned short)(r >> 16);
}
__device__ __forceinline__ float bf2f(unsigned short b) {
  union { unsigned u; float f; } v; v.u = ((unsigned)b) << 16;
  return v.f;
}
__device__ __forceinline__ float sigf(float x) { return 1.0f / (1.0f + __expf(-x)); }

__device__ __forceinline__ void glds16(const void* g, const void* l) {
  __builtin_amdgcn_global_load_lds(
      (const __attribute__((address_space(1))) unsigned int*)g,
      (__attribute__((address_space(3))) unsigned int*)l, 16, 0, 0);
}

// ---------------- sT[l*NN + n] = sum_d X[n,l,d] ----------------
__global__ __launch_bounds__(256)
void sum_rows_kernel(const float* __restrict__ X, float* __restrict__ sT) {
  int row  = blockIdx.x * 4 + (threadIdx.x >> 6);
  int lane = threadIdx.x & 63;
  const float* x = X + (size_t)row * DD + lane * 8;
  float4 a = *(const float4*)x;
  float4 b = *(const float4*)(x + 4);
  float v = (a.x + a.y) + (a.z + a.w) + (b.x + b.y) + (b.z + b.w);
#pragma unroll
  for (int off = 32; off > 0; off >>= 1) v += __shfl_down(v, off, 64);
  if (lane == 0) {
    int n = row >> 9, l = row & 511;
    sT[l * NN + n] = v;
  }
}

// ---------------- split W into bf16 hi|lo, gate-interleaved rows ----------------
__global__ __launch_bounds__(256)
void wsplit_kernel(const float* __restrict__ Wi, const float* __restrict__ Wf,
                   const float* __restrict__ Wg, const float* __restrict__ Wo,
                   unsigned short* __restrict__ B) {
  int idx = blockIdx.x * 256 + threadIdx.x;    // NJ*128 threads
  int j = idx >> 7;
  int k = (idx & 127) << 3;
  int hc = j >> 2, g = j & 3;
  const float* W = (g == 0) ? Wi : (g == 1) ? Wf : (g == 2) ? Wg : Wo;
  const float4 x0 = *(const float4*)(W + (size_t)hc * HH + k);
  const float4 x1 = *(const float4*)(W + (size_t)hc * HH + k + 4);
  float xv[8] = {x0.x, x0.y, x0.z, x0.w, x1.x, x1.y, x1.z, x1.w};
  unsigned short* dhi = B + (size_t)j * AK + k;
  unsigned short* dlo = dhi + 1024;
#pragma unroll
  for (int e = 0; e < 8; ++e) {
    unsigned short hi = f2bf(xv[e]);
    dhi[e] = hi;
    dlo[e] = f2bf(xv[e] - bf2f(hi));
  }
}

// ---------------- pack lambda / (binv+b) gate-interleaved ----------------
__global__ __launch_bounds__(256)
void pack_kernel(const float* li, const float* lf, const float* lg, const float* lo_,
                 const float* bvi, const float* bvf, const float* bvg, const float* bvo,
                 const float* bi, const float* bf_, const float* bg, const float* bo,
                 float* __restrict__ lamP, float* __restrict__ biasP) {
  int j = blockIdx.x * 256 + threadIdx.x;
  int hc = j >> 2, g = j & 3;
  const float* lam = (g == 0) ? li : (g == 1) ? lf : (g == 2) ? lg : lo_;
  const float* bv  = (g == 0) ? bvi : (g == 1) ? bvf : (g == 2) ? bvg : bvo;
  const float* bb  = (g == 0) ? bi : (g == 1) ? bf_ : (g == 2) ? bg : bo;
  lamP[j] = lam[hc];
  biasP[j] = bv[hc] + bb[hc];
}

// ---------------- t = 0 (h=0, c=0: no GEMM) ----------------
__global__ __launch_bounds__(256)
void t0_kernel(const float* __restrict__ sT, const float* __restrict__ lamP,
               const float* __restrict__ biasP, float* __restrict__ out,
               float* __restrict__ cbuf, unsigned short* __restrict__ A0) {
  int id = blockIdx.x * 256 + threadIdx.x;   // NN*HH threads
  int n = id >> 10, hc = id & 1023;
  float sv = sT[n];                          // t = 0 slice
  float4 lam = *(const float4*)(lamP + 4 * hc);
  float4 bia = *(const float4*)(biasP + 4 * hc);
  float vi = sigf(sv * lam.x + bia.x);
  float vg = sigf(sv * lam.z + bia.z);
  float vo = sigf(sv * lam.w + bia.w);
  float cn = vi * vg;
  float hn = vo * sigf(cn);
  cbuf[n * HH + hc] = cn;
  out[(size_t)n * (LL * HH) + hc] = hn;
  unsigned short hi = f2bf(hn);
  A0[(size_t)n * AK + hc] = hi;
  A0[(size_t)n * AK + 1024 + hc] = f2bf(hn - bf2f(hi));
}

// ---------------- one LSTM step ----------------
// grid 256 blocks (XCD-swizzled), block 256 thr = 4 waves.
// block tile: 32 m x 64 j x K1024. wave tile: 32m x 32j x K512 (wj = w&1
// splits j, wk = w>>1 splits K). 16x16x32 MFMA, 3-product markidis.
// Per K32 slice: 8 ds_read_b128 feed 12 MFMAs (0.67 reads/MFMA vs 1.0 in R4).
// K-halves reduced via padded LDS accbuf; R4's staging/vmcnt schedule verbatim.
__global__ __launch_bounds__(256, 1)
void step_kernel(const unsigned short* __restrict__ Aprev,
                 const unsigned short* __restrict__ Bbuf,
                 const float* __restrict__ sT, const float* __restrict__ lamP,
                 const float* __restrict__ biasP, float* __restrict__ out,
                 float* __restrict__ cbuf, unsigned short* __restrict__ Acur, int t)
{
  __shared__ alignas(16) short lds[2][24576];    // 48 KB x 2
  __shared__ alignas(16) float accbuf[2][32][68]; // 17.4 KB K-half partials

  const int tid = threadIdx.x;
  const int ln  = tid & 63;
  const int w   = tid >> 6;          // wave 0..3
  const int wj  = w & 1;             // j-half
  const int wk  = w >> 1;            // K-half

  // XCD-contiguous mapping: XCD x owns Nt in [8x, 8x+8)
  const int bid = blockIdx.x;
  const int wl  = (bid & 7) * 32 + (bid >> 3);
  const int Nt  = wl >> 2;           // 0..63  (j tile)
  const int Mt  = wl & 3;            // 0..3   (m tile)
  const int n0  = Mt * 32;
  const int j0  = Nt * 64;

  // --- staging piece table: 48 pieces of 1KB; wave w owns [12w, 12w+12) (R4) ---
  const char* srcb[12];
  int ldsoff[12];
  {
    const int ps = ln & 15;
    const int rr = ln >> 4;
#pragma unroll
    for (int i = 0; i < 12; ++i) {
      int p = w * 12 + i;
      const char* s; int off;
      if (p < 8)       { int r = p * 4 + rr;        int sp = (ps & 8) | ((ps ^ r) & 7);
                         s = (const char*)(Aprev + (size_t)(n0 + r) * AK + sp * 8);
                         off = AHI + p * 512; }
      else if (p < 16) { int r = (p - 8) * 4 + rr;  int sp = (ps & 8) | ((ps ^ r) & 7);
                         s = (const char*)(Aprev + (size_t)(n0 + r) * AK + 1024 + sp * 8);
                         off = ALO + (p - 8) * 512; }
      else if (p < 32) { int r = (p - 16) * 4 + rr; int sp = (ps & 8) | ((ps ^ r) & 7);
                         s = (const char*)(Bbuf + (size_t)(j0 + r) * AK + sp * 8);
                         off = BHI + (p - 16) * 512; }
      else             { int r = (p - 32) * 4 + rr; int sp = (ps & 8) | ((ps ^ r) & 7);
                         s = (const char*)(Bbuf + (size_t)(j0 + r) * AK + 1024 + sp * 8);
                         off = BLO + (p - 32) * 512; }
      srcb[i] = s; ldsoff[i] = off;
    }
  }

  // --- fragment read offsets (shorts, within a plane; R4 swizzle) ---
  int aoff[2][4], boff[2][4];
#pragma unroll
  for (int mf = 0; mf < 2; ++mf)
#pragma unroll
    for (int sl = 0; sl < 4; ++sl) {
      int rA = mf * 16 + (ln & 15);
      int s  = sl * 4 + (ln >> 4);
      aoff[mf][sl] = rA * 128 + (((s & 8) | ((s ^ rA) & 7)) << 3);
    }
#pragma unroll
  for (int jf = 0; jf < 2; ++jf)
#pragma unroll
    for (int sl = 0; sl < 4; ++sl) {
      int rB = wj * 32 + jf * 16 + (ln & 15);
      int s  = sl * 4 + (ln >> 4);
      boff[jf][sl] = rB * 128 + (((s & 8) | ((s ^ rB) & 7)) << 3);
    }

  f32x4 a00 = {0.f,0.f,0.f,0.f}, a01 = {0.f,0.f,0.f,0.f};
  f32x4 a10 = {0.f,0.f,0.f,0.f}, a11 = {0.f,0.f,0.f,0.f};

  auto stage = [&](int c, int b) {
    const int co = c * 256;            // uniform byte offset for all pieces
#pragma unroll
    for (int i = 0; i < 12; ++i) glds16(srcb[i] + co, &lds[b][ldsoff[i]]);
  };

  auto writeacc = [&]() {
    const int rbq = (ln >> 4) * 4;
    const int jlb = wj * 32 + (ln & 15);
#pragma unroll
    for (int mf = 0; mf < 2; ++mf)
#pragma unroll
      for (int jf = 0; jf < 2; ++jf) {
        const f32x4& a = (mf == 0) ? (jf == 0 ? a00 : a01)
                                   : (jf == 0 ? a10 : a11);
#pragma unroll
        for (int r = 0; r < 4; ++r)
          accbuf[wk][mf * 16 + rbq + r][jlb + jf * 16] = a[r];
      }
  };

  stage(0, 0);
#pragma unroll
  for (int c = 0; c < NCH; ++c) {
    const int b = c & 1;
    __builtin_amdgcn_s_barrier();               // prev compute done: buf b^1 free
    if (c < NCH - 1) {
      stage(c + 1, b ^ 1);
      asm volatile("s_waitcnt vmcnt(12)" ::: "memory");  // chunk c landed; c+1 in flight
    } else {
      asm volatile("s_waitcnt vmcnt(0)" ::: "memory");
    }
    __builtin_amdgcn_s_barrier();               // all waves see chunk c
    if (wk == (c >> 2)) {
      __builtin_amdgcn_s_setprio(1);
#pragma unroll
      for (int sl = 0; sl < 4; ++sl) {
        short8 ahi0 = *(const short8*)&lds[b][AHI + aoff[0][sl]];
        short8 ahi1 = *(const short8*)&lds[b][AHI + aoff[1][sl]];
        short8 alo0 = *(const short8*)&lds[b][ALO + aoff[0][sl]];
        short8 alo1 = *(const short8*)&lds[b][ALO + aoff[1][sl]];
        short8 bh0  = *(const short8*)&lds[b][BHI + boff[0][sl]];
        short8 bh1  = *(const short8*)&lds[b][BHI + boff[1][sl]];
        short8 bl0  = *(const short8*)&lds[b][BLO + boff[0][sl]];
        short8 bl1  = *(const short8*)&lds[b][BLO + boff[1][sl]];
        a00 = __builtin_amdgcn_mfma_f32_16x16x32_bf16(ahi0, bh0, a00, 0, 0, 0);
        a00 = __builtin_amdgcn_mfma_f32_16x16x32_bf16(ahi0, bl0, a00, 0, 0, 0);
        a00 = __builtin_amdgcn_mfma_f32_16x16x32_bf16(alo0, bh0, a00, 0, 0, 0);
        a01 = __builtin_amdgcn_mfma_f32_16x16x32_bf16(ahi0, bh1, a01, 0, 0, 0);
        a01 = __builtin_amdgcn_mfma_f32_16x16x32_bf16(ahi0, bl1, a01, 0, 0, 0);
        a01 = __builtin_amdgcn_mfma_f32_16x16x32_bf16(alo0, bh1, a01, 0, 0, 0);
        a10 = __builtin_amdgcn_mfma_f32_16x16x32_bf16(ahi1, bh0, a10, 0, 0, 0);
        a10 = __builtin_amdgcn_mfma_f32_16x16x32_bf16(ahi1, bl0, a10, 0, 0, 0);
        a10 = __builtin_amdgcn_mfma_f32_16x16x32_bf16(alo1, bh0, a10, 0, 0, 0);
        a11 = __builtin_amdgcn_mfma_f32_16x16x32_bf16(ahi1, bh1, a11, 0, 0, 0);
        a11 = __builtin_amdgcn_mfma_f32_16x16x32_bf16(ahi1, bl1, a11, 0, 0, 0);
        a11 = __builtin_amdgcn_mfma_f32_16x16x32_bf16(alo1, bh1, a11, 0, 0, 0);
      }
      __builtin_amdgcn_s_setprio(0);
      if (c == 3 || c == 7) writeacc();         // last compute chunk of this K-half
    }
  }

  __syncthreads();                              // accbuf complete

  // ---- epilogue: reduce K-halves, fuse 4 gates (adjacent lanes) -> c,h ----
  const int jj = j0 + w * 16 + (ln & 15);
  const float lamv = lamP[jj];
  const float biav = biasP[jj];
  const int rbase = (ln >> 4) * 4;
  const int jl = w * 16 + (ln & 15);
#pragma unroll
  for (int mf = 0; mf < 2; ++mf) {
    const int m0 = n0 + mf * 16 + rbase;
#pragma unroll
    for (int r = 0; r < 4; ++r) {
      const int m = m0 + r;
      const int ml = mf * 16 + rbase + r;
      float a = accbuf[0][ml][jl] + accbuf[1][ml][jl];
      float v = sigf(a + sT[t * NN + m] * lamv + biav);
      const int base = ln & ~3;
      float vi = __shfl(v, base + 0, 64);
      float vf = __shfl(v, base + 1, 64);
      float vg = __shfl(v, base + 2, 64);
      float vo = __shfl(v, base + 3, 64);
      if ((ln & 3) == 0) {
        const int hc = jj >> 2;
        float cold = cbuf[m * HH + hc];
        float cn = vf * cold + vi * vg;
        float hn = vo * sigf(cn);
        cbuf[m * HH + hc] = cn;
        out[(size_t)m * (LL * HH) + (size_t)t * HH + hc] = hn;
        unsigned short h2 = f2bf(hn);
        Acur[(size_t)m * AK + hc] = h2;
        Acur[(size_t)m * AK + 1024 + hc] = f2bf(hn - bf2f(h2));
      }
    }
  }
}

extern "C" void kernel_launch(void* const* d_in, const int* in_sizes, int n_in,
                              void* d_out, int out_size, void* d_ws, size_t ws_size,
                              hipStream_t stream) {
  const float* X    = (const float*)d_in[0];
  const float* lami = (const float*)d_in[1];
  const float* bvi  = (const float*)d_in[2];
  const float* Wi   = (const float*)d_in[3];
  const float* bi   = (const float*)d_in[4];
  const float* lamf = (const float*)d_in[5];
  const float* bvf  = (const float*)d_in[6];
  const float* Wf   = (const float*)d_in[7];
  const float* bf_  = (const float*)d_in[8];
  const float* lamg = (const float*)d_in[9];
  const float* bvg  = (const float*)d_in[10];
  const float* Wg   = (const float*)d_in[11];
  const float* bg   = (const float*)d_in[12];
  const float* lamo = (const float*)d_in[13];
  const float* bvo  = (const float*)d_in[14];
  const float* Wo   = (const float*)d_in[15];
  const float* bo   = (const float*)d_in[16];

  float* out  = (float*)d_out;

  // workspace layout (~18.2 MB)
  float* cbuf  = (float*)d_ws;                         // 128*1024 f32
  float* sT    = cbuf + (size_t)NN * HH;               // 512*128  f32
  float* lamP  = sT + (size_t)NN * LL;                 // 4096 f32
  float* biasP = lamP + NJ;                            // 4096 f32
  unsigned short* A0 = (unsigned short*)(biasP + NJ);  // 128*2048 bf16
  unsigned short* A1 = A0 + (size_t)NN * AK;           // 128*2048 bf16
  unsigned short* Bb = A1 + (size_t)NN * AK;           // 4096*2048 bf16 (16 MB)

  sum_rows_kernel<<<(NN * LL) / 4, 256, 0, stream>>>(X, sT);
  wsplit_kernel<<<(NJ * 128) / 256, 256, 0, stream>>>(Wi, Wf, Wg, Wo, Bb);
  pack_kernel<<<NJ / 256, 256, 0, stream>>>(lami, lamf, lamg, lamo,
                                            bvi, bvf, bvg, bvo,
                                            bi, bf_, bg, bo, lamP, biasP);
  t0_kernel<<<(NN * HH) / 256, 256, 0, stream>>>(sT, lamP, biasP, out, cbuf, A0);

  for (int t = 1; t < LL; ++t) {
    const unsigned short* Ap = (t & 1) ? A0 : A1;
    unsigned short* Ac = (t & 1) ? (unsigned short*)A1 : A0;
    step_kernel<<<256, 256, 0, stream>>>(Ap, Bb, sT, lamP, biasP, out, cbuf, Ac, t);
  }
}

// Round 10
// 4381.176 us; speedup vs baseline: 4.1260x; 1.8977x over previous
//
#include <hip/hip_runtime.h>
#include <cstdint>
#include <cstddef>

#define NN 128
#define LL 512
#define DD 512
#define HH 1024
#define NJ 4096            // packed gate cols, j = 4*hc + g
#define ASTR 1024          // A row stride (bf16) — hi plane only
#define BSTR 2048          // B row stride (bf16): hi[1024] | lo[1024]
#define NCH 8              // K chunks of 128

// LDS plane offsets (shorts) within one 40KB buffer
#define AHI 0
#define BHI 4096
#define BLO 12288
#define BUFS 20480

typedef __attribute__((ext_vector_type(8))) short short8;
typedef __attribute__((ext_vector_type(4))) float f32x4;

__device__ __forceinline__ unsigned short f2bf(float x) {
  union { float f; unsigned u; } v; v.f = x;
  unsigned r = v.u + 0x7FFFu + ((v.u >> 16) & 1u);
  return (unsigned short)(r >> 16);
}
__device__ __forceinline__ float bf2f(unsigned short b) {
  union { unsigned u; float f; } v; v.u = ((unsigned)b) << 16;
  return v.f;
}
__device__ __forceinline__ float sigf(float x) { return 1.0f / (1.0f + __expf(-x)); }

__device__ __forceinline__ void glds16(const void* g, const void* l) {
  __builtin_amdgcn_global_load_lds(
      (const __attribute__((address_space(1))) unsigned int*)g,
      (__attribute__((address_space(3))) unsigned int*)l, 16, 0, 0);
}

// ---------------- sT[l*NN + n] = sum_d X[n,l,d] ----------------
__global__ __launch_bounds__(256)
void sum_rows_kernel(const float* __restrict__ X, float* __restrict__ sT) {
  int row  = blockIdx.x * 4 + (threadIdx.x >> 6);
  int lane = threadIdx.x & 63;
  const float* x = X + (size_t)row * DD + lane * 8;
  float4 a = *(const float4*)x;
  float4 b = *(const float4*)(x + 4);
  float v = (a.x + a.y) + (a.z + a.w) + (b.x + b.y) + (b.z + b.w);
#pragma unroll
  for (int off = 32; off > 0; off >>= 1) v += __shfl_down(v, off, 64);
  if (lane == 0) {
    int n = row >> 9, l = row & 511;
    sT[l * NN + n] = v;
  }
}

// ---------------- split W into bf16 hi|lo, gate-interleaved rows ----------------
__global__ __launch_bounds__(256)
void wsplit_kernel(const float* __restrict__ Wi, const float* __restrict__ Wf,
                   const float* __restrict__ Wg, const float* __restrict__ Wo,
                   unsigned short* __restrict__ B) {
  int idx = blockIdx.x * 256 + threadIdx.x;    // NJ*128 threads
  int j = idx >> 7;
  int k = (idx & 127) << 3;
  int hc = j >> 2, g = j & 3;
  const float* W = (g == 0) ? Wi : (g == 1) ? Wf : (g == 2) ? Wg : Wo;
  const float4 x0 = *(const float4*)(W + (size_t)hc * HH + k);
  const float4 x1 = *(const float4*)(W + (size_t)hc * HH + k + 4);
  float xv[8] = {x0.x, x0.y, x0.z, x0.w, x1.x, x1.y, x1.z, x1.w};
  unsigned short* dhi = B + (size_t)j * BSTR + k;
  unsigned short* dlo = dhi + 1024;
#pragma unroll
  for (int e = 0; e < 8; ++e) {
    unsigned short hi = f2bf(xv[e]);
    dhi[e] = hi;
    dlo[e] = f2bf(xv[e] - bf2f(hi));
  }
}

// ---------------- pack lambda / (binv+b) gate-interleaved ----------------
__global__ __launch_bounds__(256)
void pack_kernel(const float* li, const float* lf, const float* lg, const float* lo_,
                 const float* bvi, const float* bvf, const float* bvg, const float* bvo,
                 const float* bi, const float* bf_, const float* bg, const float* bo,
                 float* __restrict__ lamP, float* __restrict__ biasP) {
  int j = blockIdx.x * 256 + threadIdx.x;
  int hc = j >> 2, g = j & 3;
  const float* lam = (g == 0) ? li : (g == 1) ? lf : (g == 2) ? lg : lo_;
  const float* bv  = (g == 0) ? bvi : (g == 1) ? bvf : (g == 2) ? bvg : bvo;
  const float* bb  = (g == 0) ? bi : (g == 1) ? bf_ : (g == 2) ? bg : bo;
  lamP[j] = lam[hc];
  biasP[j] = bv[hc] + bb[hc];
}

// ---------------- t = 0 (h=0, c=0: no GEMM) ----------------
__global__ __launch_bounds__(256)
void t0_kernel(const float* __restrict__ sT, const float* __restrict__ lamP,
               const float* __restrict__ biasP, float* __restrict__ out,
               float* __restrict__ cbuf, unsigned short* __restrict__ A0) {
  int id = blockIdx.x * 256 + threadIdx.x;   // NN*HH threads
  int n = id >> 10, hc = id & 1023;
  float sv = sT[n];                          // t = 0 slice
  float4 lam = *(const float4*)(lamP + 4 * hc);
  float4 bia = *(const float4*)(biasP + 4 * hc);
  float vi = sigf(sv * lam.x + bia.x);
  float vg = sigf(sv * lam.z + bia.z);
  float vo = sigf(sv * lam.w + bia.w);
  float cn = vi * vg;
  float hn = vo * sigf(cn);
  cbuf[n * HH + hc] = cn;
  out[(size_t)n * (LL * HH) + hc] = hn;
  A0[(size_t)n * ASTR + hc] = f2bf(hn);
}

// ---------------- one LSTM step: 2-term Markidis (hh + hl) ----------------
// grid 256 blocks (XCD-swizzled), block 256 thr = 4 waves (j-split 4x16).
// block tile 32m x 64j x K1024. A = bf16(h) single plane; B = Whi + Wlo.
// Per chunk: stage {Ahi 8KB, Bhi 16KB, Blo 16KB} (10 x 1KB pieces/wave),
// double-buffered, counted vmcnt(10). Per K32 slice per wave:
// 4 ds_read_b128 -> 4 MFMA (ahi0/1 x bhi/blo). cbuf+sT prefetched pre-loop.
__global__ __launch_bounds__(256, 1)
void step_kernel(const unsigned short* __restrict__ Aprev,
                 const unsigned short* __restrict__ Bbuf,
                 const float* __restrict__ sT, const float* __restrict__ lamP,
                 const float* __restrict__ biasP, float* __restrict__ out,
                 float* __restrict__ cbuf, unsigned short* __restrict__ Acur, int t)
{
  __shared__ alignas(16) short lds[2][BUFS];   // 40 KB x 2

  const int tid = threadIdx.x;
  const int ln  = tid & 63;
  const int w   = tid >> 6;          // wave 0..3

  // XCD-contiguous mapping: XCD x owns Nt in [8x, 8x+8)
  const int bid = blockIdx.x;
  const int wl  = (bid & 7) * 32 + (bid >> 3);
  const int Nt  = wl >> 2;           // 0..63  (j tile)
  const int Mt  = wl & 3;            // 0..3   (m tile)
  const int n0  = Mt * 32;
  const int j0  = Nt * 64;

  // --- staging piece table: 40 pieces of 1KB; wave w owns [10w, 10w+10) ---
  const char* srcb[10];
  int ldsoff[10];
  {
    const int ps = ln & 15;
    const int rr = ln >> 4;
#pragma unroll
    for (int i = 0; i < 10; ++i) {
      int p = w * 10 + i;
      const char* s; int off;
      if (p < 8)       { int r = p * 4 + rr;        int sp = (ps & 8) | ((ps ^ r) & 7);
                         s = (const char*)(Aprev + (size_t)(n0 + r) * ASTR + sp * 8);
                         off = AHI + p * 512; }
      else if (p < 24) { int r = (p - 8) * 4 + rr;  int sp = (ps & 8) | ((ps ^ r) & 7);
                         s = (const char*)(Bbuf + (size_t)(j0 + r) * BSTR + sp * 8);
                         off = BHI + (p - 8) * 512; }
      else             { int r = (p - 24) * 4 + rr; int sp = (ps & 8) | ((ps ^ r) & 7);
                         s = (const char*)(Bbuf + (size_t)(j0 + r) * BSTR + 1024 + sp * 8);
                         off = BLO + (p - 24) * 512; }
      srcb[i] = s; ldsoff[i] = off;
    }
  }

  // --- fragment read offsets (shorts, within a plane; proven swizzle) ---
  int aoff[2][4], boff[4];
#pragma unroll
  for (int mf = 0; mf < 2; ++mf)
#pragma unroll
    for (int sl = 0; sl < 4; ++sl) {
      int rA = mf * 16 + (ln & 15);
      int s  = sl * 4 + (ln >> 4);
      aoff[mf][sl] = rA * 128 + (((s & 8) | ((s ^ rA) & 7)) << 3);
    }
  {
    int rB = w * 16 + (ln & 15);
#pragma unroll
    for (int sl = 0; sl < 4; ++sl) {
      int s = sl * 4 + (ln >> 4);
      boff[sl] = rB * 128 + (((s & 8) | ((s ^ rB) & 7)) << 3);
    }
  }

  // --- epilogue constants + prefetch (hide L2 latency under the K-loop) ---
  const int jj = j0 + w * 16 + (ln & 15);
  const float lamv = lamP[jj];
  const float biav = biasP[jj];
  const int rbase = (ln >> 4) * 4;
  const int hc = jj >> 2;
  float cold[2][4], svp[2][4];
#pragma unroll
  for (int mf = 0; mf < 2; ++mf)
#pragma unroll
    for (int r = 0; r < 4; ++r) {
      const int m = n0 + mf * 16 + rbase + r;
      cold[mf][r] = cbuf[m * HH + hc];
      svp[mf][r]  = sT[t * NN + m];
    }

  f32x4 acc0 = {0.f,0.f,0.f,0.f};
  f32x4 acc1 = {0.f,0.f,0.f,0.f};

  auto stage = [&](int c, int b) {
    const int co = c * 256;            // uniform byte offset for all pieces
#pragma unroll
    for (int i = 0; i < 10; ++i) glds16(srcb[i] + co, &lds[b][ldsoff[i]]);
  };

  stage(0, 0);
#pragma unroll
  for (int c = 0; c < NCH; ++c) {
    const int b = c & 1;
    __builtin_amdgcn_s_barrier();               // prev compute done: buf b^1 free
    if (c < NCH - 1) {
      stage(c + 1, b ^ 1);
      asm volatile("s_waitcnt vmcnt(10)" ::: "memory");  // chunk c landed; c+1 in flight
    } else {
      asm volatile("s_waitcnt vmcnt(0)" ::: "memory");
    }
    __builtin_amdgcn_s_barrier();               // all waves see chunk c
#pragma unroll
    for (int sl = 0; sl < 4; ++sl) {
      short8 a0 = *(const short8*)&lds[b][AHI + aoff[0][sl]];
      short8 a1 = *(const short8*)&lds[b][AHI + aoff[1][sl]];
      short8 bh = *(const short8*)&lds[b][BHI + boff[sl]];
      short8 bl = *(const short8*)&lds[b][BLO + boff[sl]];
      acc0 = __builtin_amdgcn_mfma_f32_16x16x32_bf16(a0, bh, acc0, 0, 0, 0);
      acc0 = __builtin_amdgcn_mfma_f32_16x16x32_bf16(a0, bl, acc0, 0, 0, 0);
      acc1 = __builtin_amdgcn_mfma_f32_16x16x32_bf16(a1, bh, acc1, 0, 0, 0);
      acc1 = __builtin_amdgcn_mfma_f32_16x16x32_bf16(a1, bl, acc1, 0, 0, 0);
    }
  }

  // ---- epilogue: fuse 4 gates (adjacent lanes) -> c,h ; emit h + h_hi ----
#pragma unroll
  for (int mf = 0; mf < 2; ++mf) {
    const int m0 = n0 + mf * 16 + rbase;
#pragma unroll
    for (int r = 0; r < 4; ++r) {
      const int m = m0 + r;
      float a = (mf == 0) ? acc0[r] : acc1[r];
      float v = sigf(a + svp[mf][r] * lamv + biav);
      const int base = ln & ~3;
      float vi = __shfl(v, base + 0, 64);
      float vf = __shfl(v, base + 1, 64);
      float vg = __shfl(v, base + 2, 64);
      float vo = __shfl(v, base + 3, 64);
      if ((ln & 3) == 0) {
        float cn = vf * cold[mf][r] + vi * vg;
        float hn = vo * sigf(cn);
        cbuf[m * HH + hc] = cn;
        out[(size_t)m * (LL * HH) + (size_t)t * HH + hc] = hn;
        Acur[(size_t)m * ASTR + hc] = f2bf(hn);
      }
    }
  }
}

extern "C" void kernel_launch(void* const* d_in, const int* in_sizes, int n_in,
                              void* d_out, int out_size, void* d_ws, size_t ws_size,
                              hipStream_t stream) {
  const float* X    = (const float*)d_in[0];
  const float* lami = (const float*)d_in[1];
  const float* bvi  = (const float*)d_in[2];
  const float* Wi   = (const float*)d_in[3];
  const float* bi   = (const float*)d_in[4];
  const float* lamf = (const float*)d_in[5];
  const float* bvf  = (const float*)d_in[6];
  const float* Wf   = (const float*)d_in[7];
  const float* bf_  = (const float*)d_in[8];
  const float* lamg = (const float*)d_in[9];
  const float* bvg  = (const float*)d_in[10];
  const float* bg   = (const float*)d_in[12];
  const float* Wg   = (const float*)d_in[11];
  const float* lamo = (const float*)d_in[13];
  const float* bvo  = (const float*)d_in[14];
  const float* Wo   = (const float*)d_in[15];
  const float* bo   = (const float*)d_in[16];

  float* out  = (float*)d_out;

  // workspace layout (~17.6 MB)
  float* cbuf  = (float*)d_ws;                         // 128*1024 f32
  float* sT    = cbuf + (size_t)NN * HH;               // 512*128  f32
  float* lamP  = sT + (size_t)NN * LL;                 // 4096 f32
  float* biasP = lamP + NJ;                            // 4096 f32
  unsigned short* A0 = (unsigned short*)(biasP + NJ);  // 128*1024 bf16
  unsigned short* A1 = A0 + (size_t)NN * ASTR;         // 128*1024 bf16
  unsigned short* Bb = A1 + (size_t)NN * ASTR;         // 4096*2048 bf16 (16 MB)

  sum_rows_kernel<<<(NN * LL) / 4, 256, 0, stream>>>(X, sT);
  wsplit_kernel<<<(NJ * 128) / 256, 256, 0, stream>>>(Wi, Wf, Wg, Wo, Bb);
  pack_kernel<<<NJ / 256, 256, 0, stream>>>(lami, lamf, lamg, lamo,
                                            bvi, bvf, bvg, bvo,
                                            bi, bf_, bg, bo, lamP, biasP);
  t0_kernel<<<(NN * HH) / 256, 256, 0, stream>>>(sT, lamP, biasP, out, cbuf, A0);

  for (int t = 1; t < LL; ++t) {
    const unsigned short* Ap = (t & 1) ? A0 : A1;
    unsigned short* Ac = (t & 1) ? (unsigned short*)A1 : A0;
    step_kernel<<<256, 256, 0, stream>>>(Ap, Bb, sT, lamP, biasP, out, cbuf, Ac, t);
  }
}

// Round 11
// 3563.681 us; speedup vs baseline: 5.0725x; 1.2294x over previous
//
#include <hip/hip_runtime.h>
#include <cstdint>
#include <cstddef>

#define NN 128
#define LL 512
#define DD 512
#define HH 1024
#define NJ 4096            // packed gate cols, j = 4*hc + g
#define ASTR 1024          // A row stride (fp16 elems)
#define BSTR 1024          // B row stride (fp16 elems) — single plane
#define NCH 4              // K chunks of 256 (each = 2 sub-chunks of 128)

// LDS offsets (shorts) within one 48KB buffer: A [2][32][128], B [2][64][128]
#define AHI 0
#define BHI 8192
#define BUFS 24576

typedef __attribute__((ext_vector_type(8))) _Float16 half8;
typedef __attribute__((ext_vector_type(4))) float f32x4;

__device__ __forceinline__ unsigned short f2h(float x) {
  union { _Float16 h; unsigned short u; } v; v.h = (_Float16)x; return v.u;
}
__device__ __forceinline__ float sigf(float x) { return 1.0f / (1.0f + __expf(-x)); }

__device__ __forceinline__ void glds16(const void* g, const void* l) {
  __builtin_amdgcn_global_load_lds(
      (const __attribute__((address_space(1))) unsigned int*)g,
      (__attribute__((address_space(3))) unsigned int*)l, 16, 0, 0);
}

// ---------------- sT[l*NN + n] = sum_d X[n,l,d] ----------------
__global__ __launch_bounds__(256)
void sum_rows_kernel(const float* __restrict__ X, float* __restrict__ sT) {
  int row  = blockIdx.x * 4 + (threadIdx.x >> 6);
  int lane = threadIdx.x & 63;
  const float* x = X + (size_t)row * DD + lane * 8;
  float4 a = *(const float4*)x;
  float4 b = *(const float4*)(x + 4);
  float v = (a.x + a.y) + (a.z + a.w) + (b.x + b.y) + (b.z + b.w);
#pragma unroll
  for (int off = 32; off > 0; off >>= 1) v += __shfl_down(v, off, 64);
  if (lane == 0) {
    int n = row >> 9, l = row & 511;
    sT[l * NN + n] = v;
  }
}

// ---------------- pack W into fp16, gate-interleaved rows ----------------
__global__ __launch_bounds__(256)
void wpack_kernel(const float* __restrict__ Wi, const float* __restrict__ Wf,
                  const float* __restrict__ Wg, const float* __restrict__ Wo,
                  unsigned short* __restrict__ B) {
  int idx = blockIdx.x * 256 + threadIdx.x;    // NJ*128 threads
  int j = idx >> 7;
  int k = (idx & 127) << 3;
  int hc = j >> 2, g = j & 3;
  const float* W = (g == 0) ? Wi : (g == 1) ? Wf : (g == 2) ? Wg : Wo;
  const float4 x0 = *(const float4*)(W + (size_t)hc * HH + k);
  const float4 x1 = *(const float4*)(W + (size_t)hc * HH + k + 4);
  float xv[8] = {x0.x, x0.y, x0.z, x0.w, x1.x, x1.y, x1.z, x1.w};
  unsigned short* d = B + (size_t)j * BSTR + k;
#pragma unroll
  for (int e = 0; e < 8; ++e) d[e] = f2h(xv[e]);
}

// ---------------- pack lambda / (binv+b) gate-interleaved ----------------
__global__ __launch_bounds__(256)
void pack_kernel(const float* li, const float* lf, const float* lg, const float* lo_,
                 const float* bvi, const float* bvf, const float* bvg, const float* bvo,
                 const float* bi, const float* bf_, const float* bg, const float* bo,
                 float* __restrict__ lamP, float* __restrict__ biasP) {
  int j = blockIdx.x * 256 + threadIdx.x;
  int hc = j >> 2, g = j & 3;
  const float* lam = (g == 0) ? li : (g == 1) ? lf : (g == 2) ? lg : lo_;
  const float* bv  = (g == 0) ? bvi : (g == 1) ? bvf : (g == 2) ? bvg : bvo;
  const float* bb  = (g == 0) ? bi : (g == 1) ? bf_ : (g == 2) ? bg : bo;
  lamP[j] = lam[hc];
  biasP[j] = bv[hc] + bb[hc];
}

// ---------------- t = 0 (h=0, c=0: no GEMM) ----------------
__global__ __launch_bounds__(256)
void t0_kernel(const float* __restrict__ sT, const float* __restrict__ lamP,
               const float* __restrict__ biasP, float* __restrict__ out,
               float* __restrict__ cbuf, unsigned short* __restrict__ A0) {
  int id = blockIdx.x * 256 + threadIdx.x;   // NN*HH threads
  int n = id >> 10, hc = id & 1023;
  float sv = sT[n];                          // t = 0 slice
  float4 lam = *(const float4*)(lamP + 4 * hc);
  float4 bia = *(const float4*)(biasP + 4 * hc);
  float vi = sigf(sv * lam.x + bia.x);
  float vg = sigf(sv * lam.z + bia.z);
  float vo = sigf(sv * lam.w + bia.w);
  float cn = vi * vg;
  float hn = vo * sigf(cn);
  cbuf[n * HH + hc] = cn;
  out[(size_t)n * (LL * HH) + hc] = hn;
  A0[(size_t)n * ASTR + hc] = f2h(hn);
}

// ---------------- one LSTM step: fp16 single-term GEMM ----------------
// grid 256 blocks (XCD-swizzled), block 256 thr = 4 waves (j-split 4x16).
// block tile 32m x 64j x K1024. A = fp16(h); B = fp16(W) (2^-11 rel err on
// BOTH operands — strictly better than R10's bf16-h + split-W).
// K loop: 4 chunks of 256 (= 2 proven 128-col sub-planes each), double-
// buffered 48KB x2, counted vmcnt(12). Per K32 slice per wave:
// 3 ds_read_b128 -> 2 MFMA. cbuf+sT prefetched pre-loop.
__global__ __launch_bounds__(256, 1)
void step_kernel(const unsigned short* __restrict__ Aprev,
                 const unsigned short* __restrict__ Bbuf,
                 const float* __restrict__ sT, const float* __restrict__ lamP,
                 const float* __restrict__ biasP, float* __restrict__ out,
                 float* __restrict__ cbuf, unsigned short* __restrict__ Acur, int t)
{
  __shared__ alignas(16) short lds[2][BUFS];   // 48 KB x 2

  const int tid = threadIdx.x;
  const int ln  = tid & 63;
  const int w   = tid >> 6;          // wave 0..3

  // XCD-contiguous mapping: XCD x owns Nt in [8x, 8x+8)
  const int bid = blockIdx.x;
  const int wl  = (bid & 7) * 32 + (bid >> 3);
  const int Nt  = wl >> 2;           // 0..63  (j tile)
  const int Mt  = wl & 3;            // 0..3   (m tile)
  const int n0  = Mt * 32;
  const int j0  = Nt * 64;

  // --- staging piece table: 12 pieces/wave/chunk (2 subs x 6), 1KB each ---
  const char* srcb[12];
  int ldsoff[12];
  {
    const int ps = ln & 15;
    const int rr = ln >> 4;
#pragma unroll
    for (int i = 0; i < 12; ++i) {
      int sub = i >= 6;
      int p = w * 6 + (i - sub * 6);          // 0..23
      const char* s; int off;
      if (p < 8)  { int r = p * 4 + rr;       int sp = (ps & 8) | ((ps ^ r) & 7);
                    s = (const char*)(Aprev + (size_t)(n0 + r) * ASTR + sub * 128 + sp * 8);
                    off = AHI + sub * 4096 + p * 512; }
      else        { int pb = p - 8;  int r = pb * 4 + rr;
                    int sp = (ps & 8) | ((ps ^ r) & 7);
                    s = (const char*)(Bbuf + (size_t)(j0 + r) * BSTR + sub * 128 + sp * 8);
                    off = BHI + sub * 8192 + pb * 512; }
      srcb[i] = s; ldsoff[i] = off;
    }
  }

  // --- fragment read offsets (shorts; proven 128-col swizzle per sub) ---
  int aoff[2][8], boff[8];
  {
    const int hs = ln >> 4;
#pragma unroll
    for (int sl = 0; sl < 8; ++sl) {
      int sub = sl >> 2;
      int s   = (sl & 3) * 4 + hs;
#pragma unroll
      for (int mf = 0; mf < 2; ++mf) {
        int rA = mf * 16 + (ln & 15);
        aoff[mf][sl] = AHI + sub * 4096 + rA * 128 + (((s & 8) | ((s ^ rA) & 7)) << 3);
      }
      int rB = w * 16 + (ln & 15);
      boff[sl] = BHI + sub * 8192 + rB * 128 + (((s & 8) | ((s ^ rB) & 7)) << 3);
    }
  }

  // --- epilogue constants + prefetch (hide L2 latency under the K-loop) ---
  const int jj = j0 + w * 16 + (ln & 15);
  const float lamv = lamP[jj];
  const float biav = biasP[jj];
  const int rbase = (ln >> 4) * 4;
  const int hc = jj >> 2;
  float cold[2][4], svp[2][4];
#pragma unroll
  for (int mf = 0; mf < 2; ++mf)
#pragma unroll
    for (int r = 0; r < 4; ++r) {
      const int m = n0 + mf * 16 + rbase + r;
      cold[mf][r] = cbuf[m * HH + hc];
      svp[mf][r]  = sT[t * NN + m];
    }

  f32x4 acc0 = {0.f,0.f,0.f,0.f};
  f32x4 acc1 = {0.f,0.f,0.f,0.f};

  auto stage = [&](int c, int b) {
    const int co = c * 512;            // K256 chunk = 512 B per row
#pragma unroll
    for (int i = 0; i < 12; ++i) glds16(srcb[i] + co, &lds[b][ldsoff[i]]);
  };

  stage(0, 0);
#pragma unroll
  for (int c = 0; c < NCH; ++c) {
    const int b = c & 1;
    __builtin_amdgcn_s_barrier();               // prev compute done: buf b^1 free
    if (c < NCH - 1) {
      stage(c + 1, b ^ 1);
      asm volatile("s_waitcnt vmcnt(12)" ::: "memory");  // chunk c landed; c+1 in flight
    } else {
      asm volatile("s_waitcnt vmcnt(0)" ::: "memory");
    }
    __builtin_amdgcn_s_barrier();               // all waves see chunk c
#pragma unroll
    for (int sl = 0; sl < 8; ++sl) {
      half8 a0 = *(const half8*)&lds[b][aoff[0][sl]];
      half8 a1 = *(const half8*)&lds[b][aoff[1][sl]];
      half8 bb = *(const half8*)&lds[b][boff[sl]];
      acc0 = __builtin_amdgcn_mfma_f32_16x16x32_f16(a0, bb, acc0, 0, 0, 0);
      acc1 = __builtin_amdgcn_mfma_f32_16x16x32_f16(a1, bb, acc1, 0, 0, 0);
    }
  }

  // ---- epilogue: fuse 4 gates (adjacent lanes) -> c,h ; emit h + h_fp16 ----
#pragma unroll
  for (int mf = 0; mf < 2; ++mf) {
    const int m0 = n0 + mf * 16 + rbase;
#pragma unroll
    for (int r = 0; r < 4; ++r) {
      const int m = m0 + r;
      float a = (mf == 0) ? acc0[r] : acc1[r];
      float v = sigf(a + svp[mf][r] * lamv + biav);
      const int base = ln & ~3;
      float vi = __shfl(v, base + 0, 64);
      float vf = __shfl(v, base + 1, 64);
      float vg = __shfl(v, base + 2, 64);
      float vo = __shfl(v, base + 3, 64);
      if ((ln & 3) == 0) {
        float cn = vf * cold[mf][r] + vi * vg;
        float hn = vo * sigf(cn);
        cbuf[m * HH + hc] = cn;
        out[(size_t)m * (LL * HH) + (size_t)t * HH + hc] = hn;
        Acur[(size_t)m * ASTR + hc] = f2h(hn);
      }
    }
  }
}

extern "C" void kernel_launch(void* const* d_in, const int* in_sizes, int n_in,
                              void* d_out, int out_size, void* d_ws, size_t ws_size,
                              hipStream_t stream) {
  const float* X    = (const float*)d_in[0];
  const float* lami = (const float*)d_in[1];
  const float* bvi  = (const float*)d_in[2];
  const float* Wi   = (const float*)d_in[3];
  const float* bi   = (const float*)d_in[4];
  const float* lamf = (const float*)d_in[5];
  const float* bvf  = (const float*)d_in[6];
  const float* Wf   = (const float*)d_in[7];
  const float* bf_  = (const float*)d_in[8];
  const float* lamg = (const float*)d_in[9];
  const float* bvg  = (const float*)d_in[10];
  const float* Wg   = (const float*)d_in[11];
  const float* bg   = (const float*)d_in[12];
  const float* lamo = (const float*)d_in[13];
  const float* bvo  = (const float*)d_in[14];
  const float* Wo   = (const float*)d_in[15];
  const float* bo   = (const float*)d_in[16];

  float* out  = (float*)d_out;

  // workspace layout (~9.7 MB)
  float* cbuf  = (float*)d_ws;                         // 128*1024 f32
  float* sT    = cbuf + (size_t)NN * HH;               // 512*128  f32
  float* lamP  = sT + (size_t)NN * LL;                 // 4096 f32
  float* biasP = lamP + NJ;                            // 4096 f32
  unsigned short* A0 = (unsigned short*)(biasP + NJ);  // 128*1024 fp16
  unsigned short* A1 = A0 + (size_t)NN * ASTR;         // 128*1024 fp16
  unsigned short* Bb = A1 + (size_t)NN * ASTR;         // 4096*1024 fp16 (8 MB)

  sum_rows_kernel<<<(NN * LL) / 4, 256, 0, stream>>>(X, sT);
  wpack_kernel<<<(NJ * 128) / 256, 256, 0, stream>>>(Wi, Wf, Wg, Wo, Bb);
  pack_kernel<<<NJ / 256, 256, 0, stream>>>(lami, lamf, lamg, lamo,
                                            bvi, bvf, bvg, bvo,
                                            bi, bf_, bg, bo, lamP, biasP);
  t0_kernel<<<(NN * HH) / 256, 256, 0, stream>>>(sT, lamP, biasP, out, cbuf, A0);

  for (int t = 1; t < LL; ++t) {
    const unsigned short* Ap = (t & 1) ? A0 : A1;
    unsigned short* Ac = (t & 1) ? (unsigned short*)A1 : A0;
    step_kernel<<<256, 256, 0, stream>>>(Ap, Bb, sT, lamP, biasP, out, cbuf, Ac, t);
  }
}